// Round 4
// baseline (501.121 us; speedup 1.0000x reference)
//
#include <hip/hip_runtime.h>

#define NSTEP 10

// Load one 16-float image row as 4x float4.
__device__ __forceinline__ void load_row(const float* __restrict__ p, float* r) {
    const float4* q = reinterpret_cast<const float4*>(p);
    float4 a = q[0], b = q[1], c = q[2], d = q[3];
    r[0]=a.x;  r[1]=a.y;  r[2]=a.z;  r[3]=a.w;
    r[4]=b.x;  r[5]=b.y;  r[6]=b.z;  r[7]=b.w;
    r[8]=c.x;  r[9]=c.y;  r[10]=c.z; r[11]=c.w;
    r[12]=d.x; r[13]=d.y; r[14]=d.z; r[15]=d.w;
}

// Fully-fused SNN forward, all spike-deciding math in f64 so spike decisions
// match the harness's numpy reference (integer-valued output => any f32
// reordering that flips one borderline spike costs absmax 1.0).
// 8 threads per sample, one conv channel (256 elements) each.
__global__ __launch_bounds__(256) void snn_fused_f64(
    const float* __restrict__ x,       // [B,1,16,16]
    const float* __restrict__ conv_w,  // [8,1,3,3]
    const float* __restrict__ conv_b,  // [8]
    const float* __restrict__ fc_w,    // [2,2048]
    const float* __restrict__ fc_b,    // [2]
    float* __restrict__ out,           // [B,2]
    int B)
{
    // fc weights interleaved {w0_j, w1_j}; one ds_read_b64 per element,
    // broadcast across the 8 lanes of each sample group.
    __shared__ float2 fcw[2048];
    for (int j = threadIdx.x; j < 2048; j += 256)
        fcw[j] = make_float2(fc_w[j], fc_w[2048 + j]);
    __syncthreads();

    const int g  = blockIdx.x * 256 + threadIdx.x;
    const int b  = g >> 3;
    const int ch = g & 7;
    if (b >= B) return;

    double cw[9];
    #pragma unroll
    for (int k = 0; k < 9; ++k) cw[k] = (double)conv_w[ch * 9 + k];
    const double cb = (double)conv_b[ch];

    const float* xb = x + (size_t)b * 256;

    // Per-step FC partial sums, f64 (cur2 must be f64-accurate: it decides spk2).
    double sx[NSTEP], sy[NSTEP];
    #pragma unroll
    for (int t = 0; t < NSTEP; ++t) { sx[t] = 0.0; sy[t] = 0.0; }

    // Sliding 3-row window, rows kept in f32 (exact); converted at use
    // (f32->f64 is exact; unrolled loop lets the compiler CSE the cvts).
    float r0[16], r1[16], r2[16];
    #pragma unroll
    for (int k = 0; k < 16; ++k) r0[k] = 0.f;
    load_row(xb, r1);
    load_row(xb + 16, r2);

    for (int y = 0; y < 16; ++y) {
        const int jbase = ch * 256 + y * 16;
        #pragma unroll
        for (int xx = 0; xx < 16; ++xx) {
            double c = cb;
            if (xx > 0) {           // statically elided at xx==0 (zero pad)
                c = fma(cw[0], (double)r0[xx - 1], c);
                c = fma(cw[3], (double)r1[xx - 1], c);
                c = fma(cw[6], (double)r2[xx - 1], c);
            }
            c = fma(cw[1], (double)r0[xx], c);
            c = fma(cw[4], (double)r1[xx], c);
            c = fma(cw[7], (double)r2[xx], c);
            if (xx < 15) {          // statically elided at xx==15
                c = fma(cw[2], (double)r0[xx + 1], c);
                c = fma(cw[5], (double)r1[xx + 1], c);
                c = fma(cw[8], (double)r2[xx + 1], c);
            }
            const float2 w01 = fcw[jbase + xx];
            const double w0 = (double)w01.x;
            const double w1 = (double)w01.y;
            const double cm1 = c - 1.0;   // addend when previous step spiked (THR=1)
            // 10-step LIF1: reset_t = spk_{t-1} (snntorch subtract-reset).
            double mem = 0.0;
            bool spk = false;
            #pragma unroll
            for (int t = 0; t < NSTEP; ++t) {
                mem = fma(0.9, mem, spk ? cm1 : c);
                spk = mem > 1.0;
                sx[t] += spk ? w0 : 0.0;
                sy[t] += spk ? w1 : 0.0;
            }
        }
        // Slide the row window.
        #pragma unroll
        for (int k = 0; k < 16; ++k) { r0[k] = r1[k]; r1[k] = r2[k]; }
        if (y < 14) {
            load_row(xb + (y + 2) * 16, r2);
        } else {
            #pragma unroll
            for (int k = 0; k < 16; ++k) r2[k] = 0.f;
        }
    }

    // Combine the 8 per-thread (per-channel) partials of this sample.
    #pragma unroll
    for (int t = 0; t < NSTEP; ++t) {
        sx[t] += __shfl_xor(sx[t], 1);
        sy[t] += __shfl_xor(sy[t], 1);
        sx[t] += __shfl_xor(sx[t], 2);
        sy[t] += __shfl_xor(sy[t], 2);
        sx[t] += __shfl_xor(sx[t], 4);
        sy[t] += __shfl_xor(sy[t], 4);
    }

    if (ch == 0) {
        const double fb0 = (double)fc_b[0];
        const double fb1 = (double)fc_b[1];
        double m0 = 0.0, m1 = 0.0, p0 = 0.0, p1 = 0.0;
        float a0 = 0.f, a1 = 0.f;
        #pragma unroll
        for (int t = 0; t < NSTEP; ++t) {
            m0 = fma(0.9, m0, (sx[t] + fb0) - p0);
            m1 = fma(0.9, m1, (sy[t] + fb1) - p1);
            p0 = (m0 > 1.0) ? 1.0 : 0.0;
            p1 = (m1 > 1.0) ? 1.0 : 0.0;
            a0 += (float)p0;
            a1 += (float)p1;
        }
        reinterpret_cast<float2*>(out)[b] = make_float2(a0, a1);
    }
}

extern "C" void kernel_launch(void* const* d_in, const int* in_sizes, int n_in,
                              void* d_out, int out_size, void* d_ws, size_t ws_size,
                              hipStream_t stream) {
    const float* x      = (const float*)d_in[0];
    const float* conv_w = (const float*)d_in[1];
    const float* conv_b = (const float*)d_in[2];
    const float* fc_w   = (const float*)d_in[3];
    const float* fc_b   = (const float*)d_in[4];
    float* out = (float*)d_out;

    const int B = in_sizes[0] / 256;      // x is [B,1,16,16]
    const int threads = B * 8;            // 8 threads per sample (1 channel each)
    const int blocks = (threads + 255) / 256;
    snn_fused_f64<<<blocks, 256, 0, stream>>>(x, conv_w, conv_b, fc_w, fc_b, out, B);
}